// Round 8
// baseline (173.562 us; speedup 1.0000x reference)
//
#include <hip/hip_runtime.h>

// B=16, Lk=2048, Lq=256, DIM=512, HEADS=8, d_k=64 — f32 I/O, bf16 MFMA internally.
// out = softmax((G@Wq+bq) heads @ L^T * scale) @ L, merge heads, @ Wo + bo
#define KSTR 72   // attn P-buffer row stride (shorts)

typedef __attribute__((ext_vector_type(8))) short short8;  // 8 bf16 (4 VGPRs)
typedef __attribute__((ext_vector_type(4))) float f32x4;

#define EXP2F(x) __builtin_amdgcn_exp2f(x)
#define WAITV(n) asm volatile("s_waitcnt vmcnt(" #n ")" ::: "memory")
#define SCHEDB() __builtin_amdgcn_sched_barrier(0)

__device__ __forceinline__ unsigned short f2bf(float f) {   // RNE f32->bf16
    union { float f; unsigned u; } v; v.f = f;
    unsigned r = v.u + 0x7fff + ((v.u >> 16) & 1);
    return (unsigned short)(r >> 16);
}
__device__ __forceinline__ unsigned pk2(float a, float b) {
    return (unsigned)f2bf(a) | ((unsigned)f2bf(b) << 16);
}

// ---- merged prep: blocks [0,4096) do conv_L; blocks [4096,4352) do conv_W.
__global__ __launch_bounds__(256) void conv_prep(const float* __restrict__ Lmat,
                                                 const float* __restrict__ Wq,
                                                 const float* __restrict__ Wo,
                                                 unsigned short* __restrict__ KF,
                                                 unsigned short* __restrict__ VF,
                                                 unsigned short* __restrict__ WqF,
                                                 unsigned short* __restrict__ WoF) {
    const int tid = threadIdx.x;
    if (blockIdx.x >= 4096) {
        const int idx = blockIdx.x - 4096;            // [0,256)
        const float* W = (idx >> 7) ? Wo : Wq;
        unsigned short* WF = (idx >> 7) ? WoF : WqF;
        int g = (idx & 127) * 256 + tid;              // [0, 32768)
        int lane = g & 63, ntg = (g >> 6) & 31, kt = g >> 11;
        int c = lane & 15, quad = lane >> 4;
        const float* wp = W + (size_t)(32 * kt + 8 * quad) * 512 + 16 * ntg + c;
        float v[8];
        #pragma unroll
        for (int j = 0; j < 8; j++) v[j] = wp[(size_t)j * 512];
        uint4 u;
        u.x = pk2(v[0], v[1]); u.y = pk2(v[2], v[3]);
        u.z = pk2(v[4], v[5]); u.w = pk2(v[6], v[7]);
        *(uint4*)(WF + (size_t)g * 8) = u;
        return;
    }
    __shared__ unsigned short KFs[4096];
    __shared__ unsigned short VFs[4096];
    const int blk = blockIdx.x;            // ((b*8+h)*32+t)
    const int t = blk & 31, h = (blk >> 5) & 7, b = blk >> 8;
    const int key = tid & 63, wv = tid >> 6;   // 16 d's per thread

    const float* src = Lmat + ((size_t)(b * 2048 + 64 * t + key)) * 512 + 64 * h + 16 * wv;
    float4 a0 = *(const float4*)src;
    float4 a1 = *(const float4*)(src + 4);
    float4 a2 = *(const float4*)(src + 8);
    float4 a3 = *(const float4*)(src + 12);
    float vals[16] = {a0.x, a0.y, a0.z, a0.w, a1.x, a1.y, a1.z, a1.w,
                      a2.x, a2.y, a2.z, a2.w, a3.x, a3.y, a3.z, a3.w};
    #pragma unroll
    for (int i = 0; i < 16; i++) {
        int d = 16 * wv + i;
        unsigned short bv = f2bf(vals[i]);
        KFs[((((key >> 4) * 2 + (d >> 5)) * 64) + ((d >> 3) & 3) * 16 + (key & 15)) * 8 + (d & 7)] = bv;
        VFs[((((d >> 4) * 2 + (key >> 5)) * 64) + ((key >> 3) & 3) * 16 + (d & 15)) * 8 + (key & 7)] = bv;
    }
    __syncthreads();
    size_t gbase = (size_t)blk * 4096 + tid * 16;
    *(uint4*)(KF + gbase)     = *(const uint4*)&KFs[tid * 16];
    *(uint4*)(KF + gbase + 8) = *(const uint4*)&KFs[tid * 16 + 8];
    *(uint4*)(VF + gbase)     = *(const uint4*)&VFs[tid * 16];
    *(uint4*)(VF + gbase + 8) = *(const uint4*)&VFs[tid * 16 + 8];
}

// ---- barrier-free gemm: C[M,512] = (A@W + bias)*oscale. No LDS, no syncs.
template<bool A_BF16, bool OUT_BF16>
__global__ __launch_bounds__(256, 2) void gemm_direct(const void* __restrict__ Ap,
                                                      const unsigned short* __restrict__ WF,
                                                      const float* __restrict__ bias,
                                                      void* __restrict__ Cp,
                                                      float oscale) {
    const int tid = threadIdx.x;
    const int wv = tid >> 6, lane = tid & 63;
    const int c = lane & 15, quad = lane >> 4;
    const int m0 = blockIdx.x * 64, n0 = blockIdx.y * 64;
    const int row = m0 + 16 * wv + c;

    f32x4 acc[4];
    #pragma unroll
    for (int nt = 0; nt < 4; nt++) acc[nt] = (f32x4){0.f, 0.f, 0.f, 0.f};

    #pragma unroll
    for (int kk = 0; kk < 16; kk++) {
        short8 af;
        if (A_BF16) {
            af = *(const short8*)((const unsigned short*)Ap + (size_t)row * 512 + 32 * kk + 8 * quad);
        } else {
            const float* ap = (const float*)Ap + (size_t)row * 512 + 32 * kk + 8 * quad;
            float4 x0 = *(const float4*)ap;
            float4 x1 = *(const float4*)(ap + 4);
            af[0] = (short)f2bf(x0.x); af[1] = (short)f2bf(x0.y);
            af[2] = (short)f2bf(x0.z); af[3] = (short)f2bf(x0.w);
            af[4] = (short)f2bf(x1.x); af[5] = (short)f2bf(x1.y);
            af[6] = (short)f2bf(x1.z); af[7] = (short)f2bf(x1.w);
        }
        #pragma unroll
        for (int nt = 0; nt < 4; nt++) {
            short8 bf = *(const short8*)(WF +
                (((size_t)kk * 32 + (n0 >> 4) + nt) * 64 + lane) * 8);
            acc[nt] = __builtin_amdgcn_mfma_f32_16x16x32_bf16(af, bf, acc[nt], 0, 0, 0);
        }
    }

    #pragma unroll
    for (int nt = 0; nt < 4; nt++) {
        float bv = bias[n0 + 16 * nt + c];
        #pragma unroll
        for (int r = 0; r < 4; r++) {
            float v = (acc[nt][r] + bv) * oscale;
            size_t idx = (size_t)(m0 + 16 * wv + 4 * quad + r) * 512 + n0 + 16 * nt + c;
            if (OUT_BF16) ((unsigned short*)Cp)[idx] = f2bf(v);
            else          ((float*)Cp)[idx] = v;
        }
    }
}

// ---- attn: fused Q-proj + cooperative LDS staging (T3 2-phase, counted vmcnt).
// Round-7 post-mortem: attn is HBM-LATENCY-bound (64MB at 1.7 of 6.3 TB/s, all
// util counters low; ~8KB in flight per CU vs ~9.2KB needed at full duty). Fix:
// all 4 waves stage tile t's K+V (16KB) into an LDS double-buffer via
// global_load_lds (zero VGPR cost), vmcnt(4) keeps the next tile's loads in
// flight across barriers. Wave wv computes ONLY q-group wv for every tile ->
// split-K merge phase deleted (each wave owns its 16 rows end-to-end). The
// ring is a linear copy of the frag-ordered tile: ds_read_b128 at lane*16B is
// conflict-free and fragment math is unchanged.
__global__ __launch_bounds__(256, 2) void attn_frag(const float* __restrict__ G,
                                                    const unsigned short* __restrict__ WqF,
                                                    const float* __restrict__ bq,
                                                    const unsigned short* __restrict__ KF,
                                                    const unsigned short* __restrict__ VF,
                                                    unsigned short* __restrict__ X,
                                                    float SCe) {
    __shared__ unsigned short Kr[2][4096];      // 16 KB ring (K)
    __shared__ unsigned short Vr[2][4096];      // 16 KB ring (V)
    __shared__ unsigned short Pw[4][16 * KSTR]; // per-wave P (9.2 KB)
    __shared__ unsigned short Qs[64][72];       // Q exchange (9.2 KB)

    // swizzle: raw = xcd + 8*(qt + 4*grp); bh = grp*8 + xcd -> b=grp, h=xcd
    const int raw = blockIdx.x;
    const int h  = raw & 7;
    const int qt = (raw >> 3) & 3;
    const int b  = raw >> 5;
    const int tid = threadIdx.x;
    const int wv = tid >> 6, lane = tid & 63;
    const int c = lane & 15, quad = lane >> 4;
    const int n0 = h * 64;

    // ---- fused Q projection (same frag math as gemm_direct<false,true>)
    {
        f32x4 qacc[4];
        #pragma unroll
        for (int nt = 0; nt < 4; nt++) qacc[nt] = (f32x4){0.f, 0.f, 0.f, 0.f};
        const float* gbase = G + ((size_t)(b * 256 + qt * 64 + 16 * wv + c)) * 512;
        #pragma unroll
        for (int kk = 0; kk < 16; kk++) {
            const float* ap = gbase + 32 * kk + 8 * quad;
            float4 x0 = *(const float4*)ap;
            float4 x1 = *(const float4*)(ap + 4);
            short8 af;
            af[0] = (short)f2bf(x0.x); af[1] = (short)f2bf(x0.y);
            af[2] = (short)f2bf(x0.z); af[3] = (short)f2bf(x0.w);
            af[4] = (short)f2bf(x1.x); af[5] = (short)f2bf(x1.y);
            af[6] = (short)f2bf(x1.z); af[7] = (short)f2bf(x1.w);
            #pragma unroll
            for (int nt = 0; nt < 4; nt++) {
                short8 bf = *(const short8*)(WqF +
                    (((size_t)kk * 32 + (n0 >> 4) + nt) * 64 + lane) * 8);
                qacc[nt] = __builtin_amdgcn_mfma_f32_16x16x32_bf16(af, bf, qacc[nt], 0, 0, 0);
            }
        }
        #pragma unroll
        for (int nt = 0; nt < 4; nt++) {
            float bv = bq[n0 + 16 * nt + c];
            #pragma unroll
            for (int r = 0; r < 4; r++)
                Qs[16 * wv + 4 * quad + r][16 * nt + c] =
                    f2bf((qacc[nt][r] + bv) * SCe);
        }
    }
    __syncthreads();

    // this wave's q-group = wv
    short8 qa[2];
    qa[0] = *(const short8*)&Qs[16 * wv + c][8 * quad];
    qa[1] = *(const short8*)&Qs[16 * wv + c][32 + 8 * quad];

    short8 ones;
    #pragma unroll
    for (int i = 0; i < 8; i++) ones[i] = (short)0x3F80;

    f32x4 oacc[4];
    #pragma unroll
    for (int dt = 0; dt < 4; dt++) oacc[dt] = (f32x4){0.f, 0.f, 0.f, 0.f};
    f32x4 lacc = (f32x4){0.f, 0.f, 0.f, 0.f};

    const int swc = (c >> 3) & 1;
    const int swr = (quad >> 1) & 1;

    const unsigned short* kf0 = KF + ((size_t)((b * 8 + h) * 32)) * 4096;
    const unsigned short* vf0 = VF + ((size_t)((b * 8 + h) * 32)) * 4096;

    // stage tile tp into ring slot bs: 4 global_load_lds x16B per thread.
    // LDS dest = wave-uniform base + lane*16 (HW rule) -- expression matches.
#define STAGE(bs, tp) do { \
        const unsigned short* ks_ = kf0 + (size_t)(tp) * 4096 + wv * 1024 + lane * 8; \
        const unsigned short* vs_ = vf0 + (size_t)(tp) * 4096 + wv * 1024 + lane * 8; \
        __builtin_amdgcn_global_load_lds((const unsigned int*)ks_, \
            (unsigned int*)&Kr[bs][wv * 1024 + lane * 8], 16, 0, 0); \
        __builtin_amdgcn_global_load_lds((const unsigned int*)(ks_ + 512), \
            (unsigned int*)&Kr[bs][wv * 1024 + 512 + lane * 8], 16, 0, 0); \
        __builtin_amdgcn_global_load_lds((const unsigned int*)vs_, \
            (unsigned int*)&Vr[bs][wv * 1024 + lane * 8], 16, 0, 0); \
        __builtin_amdgcn_global_load_lds((const unsigned int*)(vs_ + 512), \
            (unsigned int*)&Vr[bs][wv * 1024 + 512 + lane * 8], 16, 0, 0); \
    } while (0)

    auto compute = [&](const unsigned short* kr, const unsigned short* vr) {
        short8 kbuf[8];
        #pragma unroll
        for (int f = 0; f < 8; f++) kbuf[f] = *(const short8*)(kr + f * 512 + lane * 8);
        f32x4 sacc[4];
        #pragma unroll
        for (int nt = 0; nt < 4; nt++) sacc[nt] = (f32x4){0.f, 0.f, 0.f, 0.f};
        __builtin_amdgcn_s_setprio(1);
        #pragma unroll
        for (int nt = 0; nt < 4; nt++)
            #pragma unroll
            for (int ks = 0; ks < 2; ks++)
                sacc[nt] = __builtin_amdgcn_mfma_f32_16x16x32_bf16(
                    qa[ks], kbuf[nt * 2 + ks], sacc[nt], 0, 0, 0);
        __builtin_amdgcn_s_setprio(0);
        #pragma unroll
        for (int nt = 0; nt < 4; nt++)
            #pragma unroll
            for (int r = 0; r < 4; r++)
                Pw[wv][(4 * quad + r) * KSTR + ((16 * nt + c) ^ (8 * swr))] =
                    f2bf(EXP2F(sacc[nt][r]));
        short8 pa0 = *(const short8*)&Pw[wv][c * KSTR + 8 * (quad ^ swc)];
        short8 pa1 = *(const short8*)&Pw[wv][c * KSTR + 32 + 8 * (quad ^ swc)];
        short8 vbuf[8];
        #pragma unroll
        for (int f = 0; f < 8; f++) vbuf[f] = *(const short8*)(vr + f * 512 + lane * 8);
        __builtin_amdgcn_s_setprio(1);
        #pragma unroll
        for (int dt = 0; dt < 4; dt++) {
            oacc[dt] = __builtin_amdgcn_mfma_f32_16x16x32_bf16(pa0, vbuf[dt * 2], oacc[dt], 0, 0, 0);
            oacc[dt] = __builtin_amdgcn_mfma_f32_16x16x32_bf16(pa1, vbuf[dt * 2 + 1], oacc[dt], 0, 0, 0);
        }
        lacc = __builtin_amdgcn_mfma_f32_16x16x32_bf16(pa0, ones, lacc, 0, 0, 0);
        lacc = __builtin_amdgcn_mfma_f32_16x16x32_bf16(pa1, ones, lacc, 0, 0, 0);
        __builtin_amdgcn_s_setprio(0);
    };

    // prologue: tiles 0,1 in flight (8 outstanding)
    STAGE(0, 0);
    STAGE(1, 1);
    for (int i = 0; i < 16; i++) {           // tiles 2i, 2i+1
        WAITV(4); SCHEDB();                  // tile 2i landed; 2i+1 in flight
        __syncthreads();                     // all waves' quarters visible
        compute(&Kr[0][0], &Vr[0][0]);
        __syncthreads();                     // all done reading slot 0
        if (i < 15) { STAGE(0, 2 * i + 2); WAITV(4); }
        else        { WAITV(0); }            // last pair: drain tile 31
        SCHEDB();
        __syncthreads();
        compute(&Kr[1][0], &Vr[1][0]);
        __syncthreads();
        if (i < 15) STAGE(1, 2 * i + 3);
    }

    // ---- epilogue: this wave owns rows 16wv..16wv+15 outright (no merge)
    #pragma unroll
    for (int r = 0; r < 4; r++) {
        float inv = 1.f / lacc[r];
        size_t row = (size_t)(b * 256 + qt * 64 + 16 * wv + 4 * quad + r);
        unsigned short* xp = X + row * 512 + h * 64;
        #pragma unroll
        for (int dt = 0; dt < 4; dt++)
            xp[16 * dt + c] = f2bf(oacc[dt][r] * inv);
    }
#undef STAGE
}

// ---------------------------------------------------------------------------
extern "C" void kernel_launch(void* const* d_in, const int* in_sizes, int n_in,
                              void* d_out, int out_size, void* d_ws, size_t ws_size,
                              hipStream_t stream) {
    const float* Lmat = (const float*)d_in[0];  // [16,2048,512]
    const float* G    = (const float*)d_in[1];  // [16,256,512]
    const float* Wq   = (const float*)d_in[2];  // [512,512]
    const float* bq   = (const float*)d_in[3];  // [512]
    const float* Wo   = (const float*)d_in[4];  // [512,512]
    const float* bo   = (const float*)d_in[5];  // [512]
    float* out = (float*)d_out;                 // [16,256,512] f32

    const float SCe = 0.005524271728019903f * 1.4426950408889634f;  // scale*log2e

    // ws layout (bf16 elems): Qws 2M (unused) | Xws 2M | WqF 256K | WoF 256K | KF 16M | VF 16M
    unsigned short* Qws = (unsigned short*)d_ws;
    unsigned short* Xws = Qws + (size_t)2097152;
    unsigned short* WqF = Xws + (size_t)2097152;
    unsigned short* WoF = WqF + (size_t)262144;
    unsigned short* KF  = WoF + (size_t)262144;
    unsigned short* VF  = KF  + (size_t)16777216;

    conv_prep<<<4352, 256, 0, stream>>>(Lmat, Wq, Wo, KF, VF, WqF, WoF);
    attn_frag<<<512, 256, 0, stream>>>(G, WqF, bq, KF, VF, Xws, SCe);
    gemm_direct<true, false><<<dim3(64, 8), 256, 0, stream>>>(Xws, WoF, bo, out, 1.0f);
}

// Round 9
// 167.080 us; speedup vs baseline: 1.0388x; 1.0388x over previous
//
#include <hip/hip_runtime.h>

// B=16, Lk=2048, Lq=256, DIM=512, HEADS=8, d_k=64 — f32 I/O, bf16 MFMA internally.
// out = softmax((G@Wq+bq) heads @ L^T * scale) @ L, merge heads, @ Wo + bo
#define KSTR 72   // attn P-buffer row stride (shorts)

typedef __attribute__((ext_vector_type(8))) short short8;  // 8 bf16 (4 VGPRs)
typedef __attribute__((ext_vector_type(4))) float f32x4;

#define EXP2F(x) __builtin_amdgcn_exp2f(x)
#define WAITV(n) asm volatile("s_waitcnt vmcnt(" #n ")" ::: "memory")
#define SCHEDB() __builtin_amdgcn_sched_barrier(0)

__device__ __forceinline__ unsigned short f2bf(float f) {   // RNE f32->bf16
    union { float f; unsigned u; } v; v.f = f;
    unsigned r = v.u + 0x7fff + ((v.u >> 16) & 1);
    return (unsigned short)(r >> 16);
}
__device__ __forceinline__ unsigned pk2(float a, float b) {
    return (unsigned)f2bf(a) | ((unsigned)f2bf(b) << 16);
}

// ---- merged prep: blocks [0,4096) do conv_L; blocks [4096,4352) do conv_W.
__global__ __launch_bounds__(256) void conv_prep(const float* __restrict__ Lmat,
                                                 const float* __restrict__ Wq,
                                                 const float* __restrict__ Wo,
                                                 unsigned short* __restrict__ KF,
                                                 unsigned short* __restrict__ VF,
                                                 unsigned short* __restrict__ WqF,
                                                 unsigned short* __restrict__ WoF) {
    const int tid = threadIdx.x;
    if (blockIdx.x >= 4096) {
        const int idx = blockIdx.x - 4096;            // [0,256)
        const float* W = (idx >> 7) ? Wo : Wq;
        unsigned short* WF = (idx >> 7) ? WoF : WqF;
        int g = (idx & 127) * 256 + tid;              // [0, 32768)
        int lane = g & 63, ntg = (g >> 6) & 31, kt = g >> 11;
        int c = lane & 15, quad = lane >> 4;
        const float* wp = W + (size_t)(32 * kt + 8 * quad) * 512 + 16 * ntg + c;
        float v[8];
        #pragma unroll
        for (int j = 0; j < 8; j++) v[j] = wp[(size_t)j * 512];
        uint4 u;
        u.x = pk2(v[0], v[1]); u.y = pk2(v[2], v[3]);
        u.z = pk2(v[4], v[5]); u.w = pk2(v[6], v[7]);
        *(uint4*)(WF + (size_t)g * 8) = u;
        return;
    }
    __shared__ unsigned short KFs[4096];
    __shared__ unsigned short VFs[4096];
    const int blk = blockIdx.x;            // ((b*8+h)*32+t)
    const int t = blk & 31, h = (blk >> 5) & 7, b = blk >> 8;
    const int key = tid & 63, wv = tid >> 6;   // 16 d's per thread

    const float* src = Lmat + ((size_t)(b * 2048 + 64 * t + key)) * 512 + 64 * h + 16 * wv;
    float4 a0 = *(const float4*)src;
    float4 a1 = *(const float4*)(src + 4);
    float4 a2 = *(const float4*)(src + 8);
    float4 a3 = *(const float4*)(src + 12);
    float vals[16] = {a0.x, a0.y, a0.z, a0.w, a1.x, a1.y, a1.z, a1.w,
                      a2.x, a2.y, a2.z, a2.w, a3.x, a3.y, a3.z, a3.w};
    #pragma unroll
    for (int i = 0; i < 16; i++) {
        int d = 16 * wv + i;
        unsigned short bv = f2bf(vals[i]);
        KFs[((((key >> 4) * 2 + (d >> 5)) * 64) + ((d >> 3) & 3) * 16 + (key & 15)) * 8 + (d & 7)] = bv;
        VFs[((((d >> 4) * 2 + (key >> 5)) * 64) + ((key >> 3) & 3) * 16 + (d & 15)) * 8 + (key & 7)] = bv;
    }
    __syncthreads();
    size_t gbase = (size_t)blk * 4096 + tid * 16;
    *(uint4*)(KF + gbase)     = *(const uint4*)&KFs[tid * 16];
    *(uint4*)(KF + gbase + 8) = *(const uint4*)&KFs[tid * 16 + 8];
    *(uint4*)(VF + gbase)     = *(const uint4*)&VFs[tid * 16];
    *(uint4*)(VF + gbase + 8) = *(const uint4*)&VFs[tid * 16 + 8];
}

// ---- barrier-free gemm: C[M,512] = (A@W + bias)*oscale. No LDS, no syncs.
template<bool A_BF16, bool OUT_BF16>
__global__ __launch_bounds__(256, 2) void gemm_direct(const void* __restrict__ Ap,
                                                      const unsigned short* __restrict__ WF,
                                                      const float* __restrict__ bias,
                                                      void* __restrict__ Cp,
                                                      float oscale) {
    const int tid = threadIdx.x;
    const int wv = tid >> 6, lane = tid & 63;
    const int c = lane & 15, quad = lane >> 4;
    const int m0 = blockIdx.x * 64, n0 = blockIdx.y * 64;
    const int row = m0 + 16 * wv + c;

    f32x4 acc[4];
    #pragma unroll
    for (int nt = 0; nt < 4; nt++) acc[nt] = (f32x4){0.f, 0.f, 0.f, 0.f};

    #pragma unroll
    for (int kk = 0; kk < 16; kk++) {
        short8 af;
        if (A_BF16) {
            af = *(const short8*)((const unsigned short*)Ap + (size_t)row * 512 + 32 * kk + 8 * quad);
        } else {
            const float* ap = (const float*)Ap + (size_t)row * 512 + 32 * kk + 8 * quad;
            float4 x0 = *(const float4*)ap;
            float4 x1 = *(const float4*)(ap + 4);
            af[0] = (short)f2bf(x0.x); af[1] = (short)f2bf(x0.y);
            af[2] = (short)f2bf(x0.z); af[3] = (short)f2bf(x0.w);
            af[4] = (short)f2bf(x1.x); af[5] = (short)f2bf(x1.y);
            af[6] = (short)f2bf(x1.z); af[7] = (short)f2bf(x1.w);
        }
        #pragma unroll
        for (int nt = 0; nt < 4; nt++) {
            short8 bf = *(const short8*)(WF +
                (((size_t)kk * 32 + (n0 >> 4) + nt) * 64 + lane) * 8);
            acc[nt] = __builtin_amdgcn_mfma_f32_16x16x32_bf16(af, bf, acc[nt], 0, 0, 0);
        }
    }

    #pragma unroll
    for (int nt = 0; nt < 4; nt++) {
        float bv = bias[n0 + 16 * nt + c];
        #pragma unroll
        for (int r = 0; r < 4; r++) {
            float v = (acc[nt][r] + bv) * oscale;
            size_t idx = (size_t)(m0 + 16 * wv + 4 * quad + r) * 512 + n0 + 16 * nt + c;
            if (OUT_BF16) ((unsigned short*)Cp)[idx] = f2bf(v);
            else          ((float*)Cp)[idx] = v;
        }
    }
}

// ---- attn: fused Q-proj + split-K + WAVE-PRIVATE LDS K-ring (barrier-free).
// Round-8 post-mortem: cooperative staging regressed (4 barriers/2 tiles =
// lockstep; the known 2-phase stall). This keeps round-7's split-K structure
// (wave wv: tiles wv,wv+4,.. for all 4 q-groups; K/V loaded once per block)
// and adds latency cover with ZERO registers and ZERO loop barriers:
//  - each wave owns Kring[wv][2][4096]: K(T+8) staged via 8x global_load_lds
//    into the just-freed slot at the END of iter i, consumed at i+2 (~2 tiles
//    = ~4000cy of cover vs ~900cy HBM latency).
//  - V via plain register loads: consumed at PV ~1200cy after issue; the
//    compiler's own vmcnt before PV also retires the in-flight stage late.
//  - WAITV(8) at iter top: the 8 stage-loads issued last iter stay in flight.
//  - prologue stages both slots BEFORE Q-proj so tiles 0/1 stream in under
//    the ~20Kcy Q-proj phase (round 7's serial-prologue cost).
__global__ __launch_bounds__(256, 2) void attn_frag(const float* __restrict__ G,
                                                    const unsigned short* __restrict__ WqF,
                                                    const float* __restrict__ bq,
                                                    const unsigned short* __restrict__ KF,
                                                    const unsigned short* __restrict__ VF,
                                                    unsigned short* __restrict__ X,
                                                    float SCe) {
    // [0,65536) Kring[4][2][4096] shorts | [65536,74752) Pw (Qs overlaid).
    // Merge phase: Mrg[4][64][68] f32 (69632B) overlays everything.
    __shared__ __align__(16) char shm[65536 + 9216];
    unsigned short (*Kring)[2][4096] = (unsigned short (*)[2][4096])shm;
    unsigned short (*Pw)[16 * KSTR] = (unsigned short (*)[16 * KSTR])(shm + 65536);
    unsigned short (*Qs)[72] = (unsigned short (*)[72])(shm + 65536);   // overlay Pw
    float (*Mrg)[64][68] = (float (*)[64][68])shm;

    // swizzle: raw = xcd + 8*(qt + 4*grp); bh = grp*8 + xcd -> b=grp, h=xcd
    const int raw = blockIdx.x;
    const int h  = raw & 7;
    const int qt = (raw >> 3) & 3;
    const int b  = raw >> 5;
    const int tid = threadIdx.x;
    const int wv = tid >> 6, lane = tid & 63;
    const int c = lane & 15, quad = lane >> 4;
    const int n0 = h * 64;

    const unsigned short* kf0 = KF + ((size_t)((b * 8 + h) * 32)) * 4096;
    const unsigned short* vf0 = VF + ((size_t)((b * 8 + h) * 32)) * 4096;

    // stage K tile tp into this wave's ring slot (8x 1KB, zero VGPR)
#define STAGEK(slot, tp) do { \
        const unsigned short* ks_ = kf0 + (size_t)(tp) * 4096 + lane * 8; \
        unsigned short* ld_ = &Kring[wv][slot][lane * 8]; \
        _Pragma("unroll") \
        for (int ch_ = 0; ch_ < 8; ch_++) \
            __builtin_amdgcn_global_load_lds((const unsigned int*)(ks_ + ch_ * 512), \
                (unsigned int*)(ld_ + ch_ * 512), 16, 0, 0); \
    } while (0)

    // prologue stages: tiles wv (slot 0), wv+4 (slot 1) — land under Q-proj
    STAGEK(0, wv);
    STAGEK(1, wv + 4);

    // ---- fused Q projection (same frag math as gemm_direct<false,true>)
    {
        f32x4 qacc[4];
        #pragma unroll
        for (int nt = 0; nt < 4; nt++) qacc[nt] = (f32x4){0.f, 0.f, 0.f, 0.f};
        const float* gbase = G + ((size_t)(b * 256 + qt * 64 + 16 * wv + c)) * 512;
        #pragma unroll
        for (int kk = 0; kk < 16; kk++) {
            const float* ap = gbase + 32 * kk + 8 * quad;
            float4 x0 = *(const float4*)ap;
            float4 x1 = *(const float4*)(ap + 4);
            short8 af;
            af[0] = (short)f2bf(x0.x); af[1] = (short)f2bf(x0.y);
            af[2] = (short)f2bf(x0.z); af[3] = (short)f2bf(x0.w);
            af[4] = (short)f2bf(x1.x); af[5] = (short)f2bf(x1.y);
            af[6] = (short)f2bf(x1.z); af[7] = (short)f2bf(x1.w);
            #pragma unroll
            for (int nt = 0; nt < 4; nt++) {
                short8 bf = *(const short8*)(WqF +
                    (((size_t)kk * 32 + (n0 >> 4) + nt) * 64 + lane) * 8);
                qacc[nt] = __builtin_amdgcn_mfma_f32_16x16x32_bf16(af, bf, qacc[nt], 0, 0, 0);
            }
        }
        #pragma unroll
        for (int nt = 0; nt < 4; nt++) {
            float bv = bq[n0 + 16 * nt + c];
            #pragma unroll
            for (int r = 0; r < 4; r++)
                Qs[16 * wv + 4 * quad + r][16 * nt + c] =
                    f2bf((qacc[nt][r] + bv) * SCe);
        }
    }
    __syncthreads();

    short8 qa[4][2];   // all 64 q-rows: qgrp g = rows 16g..16g+15
    #pragma unroll
    for (int g = 0; g < 4; g++) {
        qa[g][0] = *(const short8*)&Qs[16 * g + c][8 * quad];
        qa[g][1] = *(const short8*)&Qs[16 * g + c][32 + 8 * quad];
    }
    __syncthreads();   // Qs read done in ALL waves before Pw (overlaid) writes

    short8 ones;
    #pragma unroll
    for (int i = 0; i < 8; i++) ones[i] = (short)0x3F80;

    f32x4 oacc[4][4];
    #pragma unroll
    for (int g = 0; g < 4; g++)
        #pragma unroll
        for (int dt = 0; dt < 4; dt++) oacc[g][dt] = (f32x4){0.f, 0.f, 0.f, 0.f};
    f32x4 lacc[4];
    #pragma unroll
    for (int g = 0; g < 4; g++) lacc[g] = (f32x4){0.f, 0.f, 0.f, 0.f};

    const int swc = (c >> 3) & 1;
    const int swr = (quad >> 1) & 1;

    for (int i = 0; i < 8; i++) {
        const int T = wv + 4 * i;           // this wave's tile
        const int s = i & 1;
        // Slot s's stage (issued iter i-2 / prologue) is retired: the newest
        // 8 outstanding vmem ops are last iter's stage for slot s^1.
        WAITV(8); SCHEDB();

        short8 kbuf[8];
        #pragma unroll
        for (int f = 0; f < 8; f++)
            kbuf[f] = *(const short8*)&Kring[wv][s][f * 512 + lane * 8];
        const unsigned short* vt = vf0 + (size_t)T * 4096 + lane * 8;
        short8 vbuf[8];
        #pragma unroll
        for (int f = 0; f < 8; f++) vbuf[f] = *(const short8*)(vt + f * 512);

        // QK + P-store for all 4 q-groups
        #pragma unroll
        for (int g = 0; g < 4; g++) {
            f32x4 sacc[4];
            #pragma unroll
            for (int nt = 0; nt < 4; nt++) sacc[nt] = (f32x4){0.f, 0.f, 0.f, 0.f};
            __builtin_amdgcn_s_setprio(1);
            #pragma unroll
            for (int nt = 0; nt < 4; nt++)
                #pragma unroll
                for (int ks = 0; ks < 2; ks++)
                    sacc[nt] = __builtin_amdgcn_mfma_f32_16x16x32_bf16(
                        qa[g][ks], kbuf[nt * 2 + ks], sacc[nt], 0, 0, 0);
            __builtin_amdgcn_s_setprio(0);
            #pragma unroll
            for (int nt = 0; nt < 4; nt++)
                #pragma unroll
                for (int r = 0; r < 4; r++)
                    Pw[wv][(4 * quad + r) * KSTR + ((16 * nt + c) ^ (8 * swr))] =
                        f2bf(EXP2F(sacc[nt][r]));
            // PV for this q-group (Pw is wave-private; write->read in-order)
            short8 pa0 = *(const short8*)&Pw[wv][c * KSTR + 8 * (quad ^ swc)];
            short8 pa1 = *(const short8*)&Pw[wv][c * KSTR + 32 + 8 * (quad ^ swc)];
            __builtin_amdgcn_s_setprio(1);
            #pragma unroll
            for (int dt = 0; dt < 4; dt++) {
                oacc[g][dt] = __builtin_amdgcn_mfma_f32_16x16x32_bf16(pa0, vbuf[dt * 2], oacc[g][dt], 0, 0, 0);
                oacc[g][dt] = __builtin_amdgcn_mfma_f32_16x16x32_bf16(pa1, vbuf[dt * 2 + 1], oacc[g][dt], 0, 0, 0);
            }
            lacc[g] = __builtin_amdgcn_mfma_f32_16x16x32_bf16(pa0, ones, lacc[g], 0, 0, 0);
            lacc[g] = __builtin_amdgcn_mfma_f32_16x16x32_bf16(pa1, ones, lacc[g], 0, 0, 0);
            __builtin_amdgcn_s_setprio(0);
        }

        if (i < 6) STAGEK(s, T + 8);        // refill just-freed slot (used i+2)
    }

    // ---- additive split-K merge (Mrg overlays everything -> barrier first).
    __syncthreads();
    #pragma unroll
    for (int g = 0; g < 4; g++) {
        #pragma unroll
        for (int dt = 0; dt < 4; dt++)
            #pragma unroll
            for (int r = 0; r < 4; r++)
                Mrg[wv][g * 16 + 4 * quad + r][16 * dt + c] = oacc[g][dt][r];
        #pragma unroll
        for (int r = 0; r < 4; r++)
            Mrg[wv][g * 16 + 4 * quad + r][64] = lacc[g][r];   // all c same value
    }
    __syncthreads();
    {
        const int row = 16 * wv + c;   // merge-wave wv owns rows 16wv..16wv+15
        float sum[16];
        #pragma unroll
        for (int j = 0; j < 16; j++) sum[j] = 0.f;
        float lsum = 0.f;
        #pragma unroll
        for (int ws = 0; ws < 4; ws++) {
            #pragma unroll
            for (int j = 0; j < 16; j++) sum[j] += Mrg[ws][row][16 * quad + j];
            lsum += Mrg[ws][row][64];
        }
        float inv = 1.f / lsum;
        unsigned short us[16];
        #pragma unroll
        for (int j = 0; j < 16; j++) us[j] = f2bf(sum[j] * inv);
        unsigned short* xp =
            X + ((size_t)(b * 256 + qt * 64 + row)) * 512 + h * 64 + 16 * quad;
        *(uint4*)(xp)     = *(uint4*)&us[0];
        *(uint4*)(xp + 8) = *(uint4*)&us[8];
    }
#undef STAGEK
}

// ---------------------------------------------------------------------------
extern "C" void kernel_launch(void* const* d_in, const int* in_sizes, int n_in,
                              void* d_out, int out_size, void* d_ws, size_t ws_size,
                              hipStream_t stream) {
    const float* Lmat = (const float*)d_in[0];  // [16,2048,512]
    const float* G    = (const float*)d_in[1];  // [16,256,512]
    const float* Wq   = (const float*)d_in[2];  // [512,512]
    const float* bq   = (const float*)d_in[3];  // [512]
    const float* Wo   = (const float*)d_in[4];  // [512,512]
    const float* bo   = (const float*)d_in[5];  // [512]
    float* out = (float*)d_out;                 // [16,256,512] f32

    const float SCe = 0.005524271728019903f * 1.4426950408889634f;  // scale*log2e

    // ws layout (bf16 elems): Qws 2M (unused) | Xws 2M | WqF 256K | WoF 256K | KF 16M | VF 16M
    unsigned short* Qws = (unsigned short*)d_ws;
    unsigned short* Xws = Qws + (size_t)2097152;
    unsigned short* WqF = Xws + (size_t)2097152;
    unsigned short* WoF = WqF + (size_t)262144;
    unsigned short* KF  = WoF + (size_t)262144;
    unsigned short* VF  = KF  + (size_t)16777216;

    conv_prep<<<4352, 256, 0, stream>>>(Lmat, Wq, Wo, KF, VF, WqF, WoF);
    attn_frag<<<512, 256, 0, stream>>>(G, WqF, bq, KF, VF, Xws, SCe);
    gemm_direct<true, false><<<dim3(64, 8), 256, 0, stream>>>(Xws, WoF, bo, out, 1.0f);
}